// Round 10
// baseline (254.895 us; speedup 1.0000x reference)
//
#include <hip/hip_runtime.h>
#include <cstdint>
#include <cstddef>

#define CAP 48
#define NSP 119
#define CPAD 16   // padded cnt stride (ints) = 64B/counter

__device__ constexpr int IDX2[9]  = {0,1,2, 1,3,4, 2,4,5};
__device__ constexpr int IDX3[27] = {0,1,2, 1,3,4, 2,4,5,
                                     1,3,4, 3,6,7, 4,7,8,
                                     2,4,5, 4,7,8, 5,8,9};
__device__ constexpr int PR2[15] = {0,1,1,2,2,2,3,3,3,3,4,4,4,4,4};
__device__ constexpr int PS2[15] = {0,0,1,0,1,2,0,1,2,3,0,1,2,3,4};
__device__ constexpr int CB4[15] = {50,51,52,54,55,57,60,61,63,66,70,71,73,76,80};

__global__ __launch_bounds__(256) void rz_pack_kernel(
    const float* __restrict__ R, const int* __restrict__ Z,
    float4* __restrict__ RZ, int n_atoms)
{
    int t = blockIdx.x * blockDim.x + threadIdx.x;
    if (t >= n_atoms) return;
    RZ[t] = make_float4(R[3*t], R[3*t+1], R[3*t+2], __int_as_float(Z[t]));
}

__global__ __launch_bounds__(256) void pad_w_kernel(
    const float* __restrict__ W, float* __restrict__ Wp, int n_el)
{
    int t = blockIdx.x * blockDim.x + threadIdx.x;
    if (t >= n_el) return;
    int rc = t / 36;
    int u  = t - rc * 36;
    Wp[t] = (u < 35) ? W[rc * 35 + u] : 0.f;
}

// ---------- phase 1: LIGHT edge scatter — 16B payload {dx,dy,dz,Zi} ----------
__global__ __launch_bounds__(256) void edge_light_kernel(
    const int* __restrict__ nbr, const float4* __restrict__ RZ,
    int* __restrict__ cnt, float4* __restrict__ pay, int n_edges)
{
    int e = blockIdx.x * blockDim.x + threadIdx.x;
    if (e >= n_edges) return;
    int i = nbr[e];
    int j = nbr[n_edges + e];
    if (i == j) return;
    float4 rzi = RZ[i];
    float4 rzj = RZ[j];
    float dx = rzj.x - rzi.x, dy = rzj.y - rzi.y, dz = rzj.z - rzi.z;
    float dr2 = dx*dx + dy*dy + dz*dz;
    if (!(dr2 < 36.0f)) return;          // cutoff == 0 outside R_MAX

    int pos = atomicAdd(&cnt[j * CPAD], 1);
    if (pos < CAP) {
        pay[(size_t)j * CAP + pos] = make_float4(dx, dy, dz, rzi.w); // rzi.w = Zi bits
    }
}

// ---------- phase 2: slot-parallel finalize; zero-fills empty slots ----------
__global__ __launch_bounds__(192) void expand_kernel(
    const int* __restrict__ Z,
    const int* __restrict__ cnt, float4* __restrict__ pay,
    const float4* __restrict__ Wp4,
    float4* __restrict__ radB, int n_atoms)
{
    int tid = threadIdx.x;
    int a    = blockIdx.x * 4 + tid / CAP;
    int slot = tid % CAP;
    if (a >= n_atoms) return;
    int cn = cnt[a * CPAD]; if (cn > CAP) cn = CAP;

    size_t idx = (size_t)a * CAP + slot;
    if (slot >= cn) {
        // empty slot: rv == 0 makes the edge contribution identically zero
        pay[idx]  = make_float4(0.f, 0.f, 0.f, 0.f);
        radB[idx] = make_float4(0.f, 0.f, 0.f, 0.f);
        return;
    }

    float4 q = pay[idx];
    float dr = sqrtf(q.x*q.x + q.y*q.y + q.z*q.z);
    float inv = 1.0f / (dr + 1e-5f);

    const float betta      = 49.0f/36.0f;
    const float rad_norm   = 0.96481270f;
    const float embed_norm = 0.37796447f;
    const float PI_F       = 3.14159265358979f;
    float cut = 0.5f * (__cosf(PI_F * dr * (1.0f/6.0f)) + 1.0f) * rad_norm * embed_norm;

    float basis[7];
    #pragma unroll
    for (int n = 0; n < 7; n++) {
        float d = dr - (0.5f + (5.5f/7.0f) * (float)n);
        basis[n] = __expf(-betta * d * d);
    }

    int zi = __float_as_int(q.w);
    int za = Z[a];
    int base4 = (zi * NSP + za) * 9;

    float rad[5] = {0,0,0,0,0};
    #pragma unroll
    for (int qq = 0; qq < 9; qq++) {
        float4 wq = Wp4[base4 + qq];
        #pragma unroll
        for (int c = 0; c < 4; c++) {
            int f = 4*qq + c;
            if (f < 35) {
                float wv = (c==0) ? wq.x : (c==1) ? wq.y : (c==2) ? wq.z : wq.w;
                rad[f/7] += basis[f%7] * wv;
            }
        }
    }
    // finalize: fold cut into rv; write {dn, rv4} over own slot + {rv0..3}
    pay[idx]  = make_float4(q.x*inv, q.y*inv, q.z*inv, rad[4]*cut);
    radB[idx] = make_float4(rad[0]*cut, rad[1]*cut, rad[2]*cut, rad[3]*cut);
}

// ---------- round-3 style fallback: scatter idx only ----------
__global__ __launch_bounds__(256) void scatter_bins_kernel(
    const int* __restrict__ nbr, int* __restrict__ cnt,
    int* __restrict__ bins, int n_edges)
{
    int e = blockIdx.x * blockDim.x + threadIdx.x;
    if (e >= n_edges) return;
    int i = nbr[e];
    int j = nbr[n_edges + e];
    if (i == j) return;
    int pos = atomicAdd(&cnt[j], 1);
    if (pos < CAP) bins[(size_t)j * CAP + pos] = i;
}

// ---------- per-edge math from raw displacement (fallback path) ----------
__device__ __forceinline__ void edge_math_raw(
    float dx, float dy, float dz, int zi, int za,
    const float4* __restrict__ Wp4, float rv[5], float dn[3])
{
    float dr = sqrtf(dx*dx + dy*dy + dz*dz);
    float inv = 1.0f / (dr + 1e-5f);
    dn[0] = dx*inv; dn[1] = dy*inv; dn[2] = dz*inv;

    const float betta      = 49.0f/36.0f;
    const float rad_norm   = 0.96481270f;
    const float embed_norm = 0.37796447f;
    const float PI_F       = 3.14159265358979f;
    float cut = 0.5f * (__cosf(PI_F * dr * (1.0f/6.0f)) + 1.0f) * rad_norm * embed_norm;

    float basis[7];
    #pragma unroll
    for (int n = 0; n < 7; n++) {
        float d = dr - (0.5f + (5.5f/7.0f) * (float)n);
        basis[n] = __expf(-betta * d * d);
    }

    int base4 = (zi * NSP + za) * 9;
    float rad[5] = {0,0,0,0,0};
    #pragma unroll
    for (int q = 0; q < 9; q++) {
        float4 wq = Wp4[base4 + q];
        #pragma unroll
        for (int c = 0; c < 4; c++) {
            int f = 4*q + c;
            if (f < 35) {
                float wv = (c==0) ? wq.x : (c==1) ? wq.y : (c==2) ? wq.z : wq.w;
                rad[f/7] += basis[f%7] * wv;
            }
        }
    }
    #pragma unroll
    for (int r = 0; r < 5; r++) rv[r] = rad[r] * cut;
}

// ---------- contraction helpers (operands in LDS) ----------
__device__ __forceinline__ void c6_range(const float* m, float* o, int plo, int phi) {
    for (int p = plo; p < phi; p++) {
        int r = PR2[p], s = PS2[p];
        const float* m3r = m + 50 + r * 10;
        const float* m3s = m + 50 + s * 10;
        float A[3][3] = {{0,0,0},{0,0,0},{0,0,0}};
        #pragma unroll
        for (int i = 0; i < 3; i++)
            #pragma unroll
            for (int j = 0; j < 3; j++)
                #pragma unroll
                for (int k = 0; k < 3; k++)
                    #pragma unroll
                    for (int l = 0; l < 3; l++)
                        A[k][l] += m3r[IDX3[(i*3+j)*3+k]] * m3s[IDX3[(i*3+j)*3+l]];
        int col = 160 + p * 5;
        for (int t = 0; t < 5; t++) {
            const float* m2t = m + 20 + t * 6;
            float acc = 0.f;
            #pragma unroll
            for (int k = 0; k < 3; k++)
                #pragma unroll
                for (int l = 0; l < 3; l++)
                    acc += A[k][l] * m2t[IDX2[k*3+l]];
            o[col + t] = acc;
        }
    }
}

__device__ __forceinline__ void c4_range(const float* m, float* o, int plo, int phi) {
    for (int p = plo; p < phi; p++) {
        int r = PR2[p], s = PS2[p];
        const float* m2r = m + 20 + r * 6;
        const float* m2s = m + 20 + s * 6;
        float B[3][3] = {{0,0,0},{0,0,0},{0,0,0}};
        #pragma unroll
        for (int i = 0; i < 3; i++)
            #pragma unroll
            for (int j = 0; j < 3; j++)
                #pragma unroll
                for (int k = 0; k < 3; k++)
                    B[j][k] += m2r[IDX2[i*3+j]] * m2s[IDX2[i*3+k]];
        int col = CB4[p];
        for (int t = 0; t <= s; t++) {
            const float* m2t = m + 20 + t * 6;
            float acc = 0.f;
            #pragma unroll
            for (int j = 0; j < 3; j++)
                #pragma unroll
                for (int k = 0; k < 3; k++)
                    acc += B[j][k] * m2t[IDX2[j*3+k]];
            o[col + t] = acc;
        }
    }
}

__device__ __forceinline__ void c5_range(const float* m, float* o, int plo, int phi) {
    for (int p = plo; p < phi; p++) {
        int r = PR2[p], s = PS2[p];
        const float* m1r = m + 5 + r * 3;
        const float* m1s = m + 5 + s * 3;
        float P[3][3];
        #pragma unroll
        for (int i = 0; i < 3; i++)
            #pragma unroll
            for (int j = 0; j < 3; j++)
                P[i][j] = m1r[i] * m1s[j];
        int col = 85 + p * 5;
        for (int t = 0; t < 5; t++) {
            const float* m2t = m + 20 + t * 6;
            float acc = 0.f;
            #pragma unroll
            for (int i = 0; i < 3; i++)
                #pragma unroll
                for (int j = 0; j < 3; j++)
                    acc += P[i][j] * m2t[IDX2[i*3+j]];
            o[col + t] = acc;
        }
    }
}

__device__ __forceinline__ void c7_all(const float* m, float* o) {
    for (int r = 0; r < 5; r++) {
        const float* m3r = m + 50 + r * 10;
        for (int s = 0; s < 5; s++) {
            const float* m2s = m + 20 + s * 6;
            float v[3] = {0,0,0};
            #pragma unroll
            for (int i = 0; i < 3; i++)
                #pragma unroll
                for (int j = 0; j < 3; j++)
                    #pragma unroll
                    for (int k = 0; k < 3; k++)
                        v[k] += m3r[IDX3[(i*3+j)*3+k]] * m2s[IDX2[i*3+j]];
            int col = 235 + (r * 5 + s) * 5;
            for (int t = 0; t < 5; t++) {
                const float* m1t = m + 5 + t * 3;
                o[col + t] = v[0]*m1t[0] + v[1]*m1t[1] + v[2]*m1t[2];
            }
        }
    }
}

__device__ __forceinline__ void c0123(const float* m, float* o) {
    for (int r = 0; r < 5; r++) o[r] = m[r];
    const float W2[6]  = {1,2,2,1,2,1};
    const float W3[10] = {1,3,3,3,6,3,1,3,3,1};
    int c1 = 5, c2 = 20, c3 = 35;
    for (int r = 0; r < 5; r++) {
        const float* a1r = m + 5 + r * 3;
        const float* a2r = m + 20 + r * 6;
        const float* a3r = m + 50 + r * 10;
        for (int s = 0; s <= r; s++) {
            const float* a1s = m + 5 + s * 3;
            const float* a2s = m + 20 + s * 6;
            const float* a3s = m + 50 + s * 10;
            float d1 = 0.f, d2 = 0.f, d3 = 0.f;
            #pragma unroll
            for (int u = 0; u < 3; u++)  d1 += a1r[u] * a1s[u];
            #pragma unroll
            for (int u = 0; u < 6; u++)  d2 += W2[u] * a2r[u] * a2s[u];
            #pragma unroll
            for (int u = 0; u < 10; u++) d3 += W3[u] * a3r[u] * a3s[u];
            o[c1++] = d1; o[c2++] = d2; o[c3++] = d3;
        }
    }
}

__device__ __forceinline__ void contract_4wave(
    float sm[64][101], int lane, int w, int a0, int n_atoms, float* __restrict__ out)
{
    int aa = a0 + lane;
    if (aa < n_atoms) {
        const float* m = sm[lane];
        float* o = out + (size_t)aa * 360;
        if (w == 0) {
            c6_range(m, o, 0, 10);
        } else if (w == 1) {
            c6_range(m, o, 10, 15);
            c4_range(m, o, 0, 7);
        } else if (w == 2) {
            c4_range(m, o, 7, 15);
            c5_range(m, o, 0, 15);
        } else {
            c7_all(m, o);
            c0123(m, o);
        }
    }
}

__device__ __forceinline__ void moments_to_out(
    float acc[100], float sm[64][101], int tid, int a0, int n_atoms,
    float* __restrict__ out)
{
    #pragma unroll
    for (int u = 0; u < 100; u++) {
        acc[u] += __shfl_xor(acc[u], 1);
        acc[u] += __shfl_xor(acc[u], 2);
    }
    int g  = tid >> 2;
    int l4 = tid & 3;
    if (a0 + g < n_atoms && l4 == 0) {
        #pragma unroll
        for (int u = 0; u < 100; u++) sm[g][u] = acc[u];
    }
    __syncthreads();
    contract_4wave(sm, tid & 63, tid >> 6, a0, n_atoms, out);
}

// accumulate the 100-moment update for one edge
__device__ __forceinline__ void accum_edge(float acc[100], const float rv[5], const float dn1[3])
{
    float p2[6] = {dn1[0]*dn1[0], dn1[0]*dn1[1], dn1[0]*dn1[2],
                   dn1[1]*dn1[1], dn1[1]*dn1[2], dn1[2]*dn1[2]};
    float p3[10] = {p2[0]*dn1[0], p2[0]*dn1[1], p2[0]*dn1[2],
                    p2[1]*dn1[1], p2[1]*dn1[2], p2[2]*dn1[2],
                    p2[3]*dn1[1], p2[3]*dn1[2], p2[4]*dn1[2],
                    p2[5]*dn1[2]};
    #pragma unroll
    for (int r = 0; r < 5; r++) {
        float rvv = rv[r];
        acc[r] += rvv;
        #pragma unroll
        for (int u = 0; u < 3; u++)  acc[5  + r*3  + u] += rvv * dn1[u];
        #pragma unroll
        for (int u = 0; u < 6; u++)  acc[20 + r*6  + u] += rvv * p2[u];
        #pragma unroll
        for (int u = 0; u < 10; u++) acc[50 + r*10 + u] += rvv * p3[u];
    }
}

// ---------- phase 3: STATIC accumulate+contract — uniform, divergence-free ----------
__global__ __launch_bounds__(256, 4) void accum_slot_kernel(
    const float4* __restrict__ pay, const float4* __restrict__ radB,
    float* __restrict__ out, int n_atoms)
{
    __shared__ float sm[64][101];
    int tid = threadIdx.x;
    int a0  = blockIdx.x * 64;
    int g   = tid >> 2;
    int l4  = tid & 3;
    int a   = a0 + g;

    float acc[100];
    #pragma unroll
    for (int u = 0; u < 100; u++) acc[u] = 0.f;

    if (a < n_atoms) {
        const float4* prow = pay  + (size_t)a * CAP;
        const float4* rrow = radB + (size_t)a * CAP;
        #pragma unroll 3
        for (int it = 0; it < CAP/4; it++) {
            int es = l4 + it * 4;
            float4 q1 = prow[es];   // {dn0, dn1, dn2, rv4}  (zeros if empty)
            float4 q2 = rrow[es];   // {rv0, rv1, rv2, rv3}
            float dn1[3] = {q1.x, q1.y, q1.z};
            float rv[5]  = {q2.x, q2.y, q2.z, q2.w, q1.w};
            accum_edge(acc, rv, dn1);
        }
    }
    moments_to_out(acc, sm, tid, a0, n_atoms, out);
}

// ---------- fallback accumulate (gather + recompute, r3/r7 style) ----------
__global__ __launch_bounds__(256) void accum_gather_kernel(
    const float4* __restrict__ RZ, const float4* __restrict__ Wp4,
    const int* __restrict__ cnt, const int* __restrict__ bins,
    float* __restrict__ out, int n_atoms)
{
    __shared__ float sm[64][101];
    int tid = threadIdx.x;
    int a0  = blockIdx.x * 64;
    int g   = tid >> 2;
    int l4  = tid & 3;
    int a   = a0 + g;

    float acc[100];
    #pragma unroll
    for (int u = 0; u < 100; u++) acc[u] = 0.f;

    if (a < n_atoms) {
        int cn = cnt[a]; if (cn > CAP) cn = CAP;
        float4 rza = RZ[a];
        int za = __float_as_int(rza.w);
        for (int e = l4; e < cn; e += 4) {
            int i = bins[(size_t)a * CAP + e];
            float4 rzi = RZ[i];
            float dx = rza.x - rzi.x, dy = rza.y - rzi.y, dz = rza.z - rzi.z;
            float dr2 = dx*dx + dy*dy + dz*dz;
            if (!(dr2 < 36.0f)) continue;
            int zi = __float_as_int(rzi.w);
            float rv[5], dn1[3];
            edge_math_raw(dx, dy, dz, zi, za, Wp4, rv, dn1);
            accum_edge(acc, rv, dn1);
        }
    }
    moments_to_out(acc, sm, tid, a0, n_atoms, out);
}

extern "C" void kernel_launch(void* const* d_in, const int* in_sizes, int n_in,
                              void* d_out, int out_size, void* d_ws, size_t ws_size,
                              hipStream_t stream)
{
    const float* R   = (const float*)d_in[0];
    const int*   Z   = (const int*)d_in[1];
    const int*   nbr = (const int*)d_in[2];
    const float* W   = (const float*)d_in[4];
    float* out = (float*)d_out;

    int n_atoms = in_sizes[0] / 3;
    int n_edges = in_sizes[2] / 2;
    int n_wel   = NSP * NSP * 36;

    char* ws = (char*)d_ws;

    size_t szCntPad = (size_t)n_atoms * CPAD * 4;       // 3.2 MB
    size_t szRZ     = (size_t)n_atoms * 16;             // 0.8 MB
    size_t szWp     = (size_t)n_wel * 4;                // 2.0 MB
    size_t szPay16  = (size_t)n_atoms * CAP * 16;       // 38.4 MB
    size_t szRadB   = (size_t)n_atoms * CAP * 16;       // 38.4 MB
    size_t szIdx    = (size_t)n_atoms * CAP * 4;        // 9.6 MB

    size_t needMain = szCntPad + szPay16 + szRadB + szRZ + szWp;   // ~82.8 MB

    if (ws_size >= needMain) {
        int*    cnt  = (int*)ws;
        float4* pay  = (float4*)(ws + szCntPad);
        float4* radB = (float4*)(ws + szCntPad + szPay16);
        float4* RZ   = (float4*)(ws + szCntPad + szPay16 + szRadB);
        float4* Wp4  = (float4*)(ws + szCntPad + szPay16 + szRadB + szRZ);

        hipMemsetAsync(cnt, 0, szCntPad, stream);
        rz_pack_kernel<<<(n_atoms + 255)/256, 256, 0, stream>>>(R, Z, RZ, n_atoms);
        pad_w_kernel<<<(n_wel + 255)/256, 256, 0, stream>>>(W, (float*)Wp4, n_wel);
        edge_light_kernel<<<(n_edges + 255)/256, 256, 0, stream>>>(
            nbr, RZ, cnt, pay, n_edges);
        expand_kernel<<<(n_atoms + 3)/4, 192, 0, stream>>>(
            Z, cnt, pay, Wp4, radB, n_atoms);
        accum_slot_kernel<<<(n_atoms + 63)/64, 256, 0, stream>>>(
            pay, radB, out, n_atoms);
    } else {
        // fallback: round-3 footprint (~14.6 MB with CAP=48)
        int*    cnt  = (int*)ws;
        int*    bins = (int*)(ws + 204800);
        float4* RZ   = (float4*)(ws + 204800 + szIdx);
        float4* Wp4  = (float4*)(ws + 204800 + szIdx + szRZ);

        hipMemsetAsync(cnt, 0, (size_t)n_atoms * 4, stream);
        rz_pack_kernel<<<(n_atoms + 255)/256, 256, 0, stream>>>(R, Z, RZ, n_atoms);
        pad_w_kernel<<<(n_wel + 255)/256, 256, 0, stream>>>(W, (float*)Wp4, n_wel);
        scatter_bins_kernel<<<(n_edges + 255)/256, 256, 0, stream>>>(nbr, cnt, bins, n_edges);
        accum_gather_kernel<<<(n_atoms + 63)/64, 256, 0, stream>>>(
            RZ, Wp4, cnt, bins, out, n_atoms);
    }
}

// Round 11
// 137.169 us; speedup vs baseline: 1.8583x; 1.8583x over previous
//
#include <hip/hip_runtime.h>
#include <cstdint>
#include <cstddef>

#define CAP 48
#define NSP 119
#define CPAD 16   // padded cnt stride (ints) = 64B/counter

__device__ constexpr int IDX2[9]  = {0,1,2, 1,3,4, 2,4,5};
__device__ constexpr int IDX3[27] = {0,1,2, 1,3,4, 2,4,5,
                                     1,3,4, 3,6,7, 4,7,8,
                                     2,4,5, 4,7,8, 5,8,9};
__device__ constexpr int PR2[15] = {0,1,1,2,2,2,3,3,3,3,4,4,4,4,4};
__device__ constexpr int PS2[15] = {0,0,1,0,1,2,0,1,2,3,0,1,2,3,4};
__device__ constexpr int CB4[15] = {50,51,52,54,55,57,60,61,63,66,70,71,73,76,80};

__global__ __launch_bounds__(256) void rz_pack_kernel(
    const float* __restrict__ R, const int* __restrict__ Z,
    float4* __restrict__ RZ, int n_atoms)
{
    int t = blockIdx.x * blockDim.x + threadIdx.x;
    if (t >= n_atoms) return;
    RZ[t] = make_float4(R[3*t], R[3*t+1], R[3*t+2], __int_as_float(Z[t]));
}

__global__ __launch_bounds__(256) void pad_w_kernel(
    const float* __restrict__ W, float* __restrict__ Wp, int n_el)
{
    int t = blockIdx.x * blockDim.x + threadIdx.x;
    if (t >= n_el) return;
    int rc = t / 36;
    int u  = t - rc * 36;
    Wp[t] = (u < 35) ? W[rc * 35 + u] : 0.f;
}

// ---------- phase 1: LIGHT edge scatter — 16B payload {dx,dy,dz,Zi} ----------
__global__ __launch_bounds__(256) void edge_light_kernel(
    const int* __restrict__ nbr, const float4* __restrict__ RZ,
    int* __restrict__ cnt, float4* __restrict__ pay, int n_edges)
{
    int e = blockIdx.x * blockDim.x + threadIdx.x;
    if (e >= n_edges) return;
    int i = nbr[e];
    int j = nbr[n_edges + e];
    if (i == j) return;
    float4 rzi = RZ[i];
    float4 rzj = RZ[j];
    float dx = rzj.x - rzi.x, dy = rzj.y - rzi.y, dz = rzj.z - rzi.z;
    float dr2 = dx*dx + dy*dy + dz*dz;
    if (!(dr2 < 36.0f)) return;          // cutoff == 0 outside R_MAX

    int pos = atomicAdd(&cnt[j * CPAD], 1);
    if (pos < CAP) {
        pay[(size_t)j * CAP + pos] = make_float4(dx, dy, dz, rzi.w); // rzi.w = Zi bits
    }
}

// ---------- phase 2: slot-parallel finalize; zero-fills empty slots ----------
__global__ __launch_bounds__(192) void expand_kernel(
    const int* __restrict__ Z,
    const int* __restrict__ cnt, float4* __restrict__ pay,
    const float4* __restrict__ Wp4,
    float4* __restrict__ radB, int n_atoms)
{
    int tid = threadIdx.x;
    int a    = blockIdx.x * 4 + tid / CAP;
    int slot = tid % CAP;
    if (a >= n_atoms) return;
    int cn = cnt[a * CPAD]; if (cn > CAP) cn = CAP;

    size_t idx = (size_t)a * CAP + slot;
    if (slot >= cn) {
        // empty slot: rv == 0 makes the edge contribution identically zero
        pay[idx]  = make_float4(0.f, 0.f, 0.f, 0.f);
        radB[idx] = make_float4(0.f, 0.f, 0.f, 0.f);
        return;
    }

    float4 q = pay[idx];
    float dr = sqrtf(q.x*q.x + q.y*q.y + q.z*q.z);
    float inv = 1.0f / (dr + 1e-5f);

    const float betta      = 49.0f/36.0f;
    const float rad_norm   = 0.96481270f;
    const float embed_norm = 0.37796447f;
    const float PI_F       = 3.14159265358979f;
    float cut = 0.5f * (__cosf(PI_F * dr * (1.0f/6.0f)) + 1.0f) * rad_norm * embed_norm;

    float basis[7];
    #pragma unroll
    for (int n = 0; n < 7; n++) {
        float d = dr - (0.5f + (5.5f/7.0f) * (float)n);
        basis[n] = __expf(-betta * d * d);
    }

    int zi = __float_as_int(q.w);
    int za = Z[a];
    int base4 = (zi * NSP + za) * 9;

    float rad[5] = {0,0,0,0,0};
    #pragma unroll
    for (int qq = 0; qq < 9; qq++) {
        float4 wq = Wp4[base4 + qq];
        #pragma unroll
        for (int c = 0; c < 4; c++) {
            int f = 4*qq + c;
            if (f < 35) {
                float wv = (c==0) ? wq.x : (c==1) ? wq.y : (c==2) ? wq.z : wq.w;
                rad[f/7] += basis[f%7] * wv;
            }
        }
    }
    // finalize: fold cut into rv; write {dn, rv4} over own slot + {rv0..3}
    pay[idx]  = make_float4(q.x*inv, q.y*inv, q.z*inv, rad[4]*cut);
    radB[idx] = make_float4(rad[0]*cut, rad[1]*cut, rad[2]*cut, rad[3]*cut);
}

// ---------- round-3 style fallback: scatter idx only ----------
__global__ __launch_bounds__(256) void scatter_bins_kernel(
    const int* __restrict__ nbr, int* __restrict__ cnt,
    int* __restrict__ bins, int n_edges)
{
    int e = blockIdx.x * blockDim.x + threadIdx.x;
    if (e >= n_edges) return;
    int i = nbr[e];
    int j = nbr[n_edges + e];
    if (i == j) return;
    int pos = atomicAdd(&cnt[j], 1);
    if (pos < CAP) bins[(size_t)j * CAP + pos] = i;
}

// ---------- per-edge math from raw displacement (fallback path) ----------
__device__ __forceinline__ void edge_math_raw(
    float dx, float dy, float dz, int zi, int za,
    const float4* __restrict__ Wp4, float rv[5], float dn[3])
{
    float dr = sqrtf(dx*dx + dy*dy + dz*dz);
    float inv = 1.0f / (dr + 1e-5f);
    dn[0] = dx*inv; dn[1] = dy*inv; dn[2] = dz*inv;

    const float betta      = 49.0f/36.0f;
    const float rad_norm   = 0.96481270f;
    const float embed_norm = 0.37796447f;
    const float PI_F       = 3.14159265358979f;
    float cut = 0.5f * (__cosf(PI_F * dr * (1.0f/6.0f)) + 1.0f) * rad_norm * embed_norm;

    float basis[7];
    #pragma unroll
    for (int n = 0; n < 7; n++) {
        float d = dr - (0.5f + (5.5f/7.0f) * (float)n);
        basis[n] = __expf(-betta * d * d);
    }

    int base4 = (zi * NSP + za) * 9;
    float rad[5] = {0,0,0,0,0};
    #pragma unroll
    for (int q = 0; q < 9; q++) {
        float4 wq = Wp4[base4 + q];
        #pragma unroll
        for (int c = 0; c < 4; c++) {
            int f = 4*q + c;
            if (f < 35) {
                float wv = (c==0) ? wq.x : (c==1) ? wq.y : (c==2) ? wq.z : wq.w;
                rad[f/7] += basis[f%7] * wv;
            }
        }
    }
    #pragma unroll
    for (int r = 0; r < 5; r++) rv[r] = rad[r] * cut;
}

// ---------- contraction helpers (operands in LDS) ----------
__device__ __forceinline__ void c6_range(const float* m, float* o, int plo, int phi) {
    for (int p = plo; p < phi; p++) {
        int r = PR2[p], s = PS2[p];
        const float* m3r = m + 50 + r * 10;
        const float* m3s = m + 50 + s * 10;
        float A[3][3] = {{0,0,0},{0,0,0},{0,0,0}};
        #pragma unroll
        for (int i = 0; i < 3; i++)
            #pragma unroll
            for (int j = 0; j < 3; j++)
                #pragma unroll
                for (int k = 0; k < 3; k++)
                    #pragma unroll
                    for (int l = 0; l < 3; l++)
                        A[k][l] += m3r[IDX3[(i*3+j)*3+k]] * m3s[IDX3[(i*3+j)*3+l]];
        int col = 160 + p * 5;
        for (int t = 0; t < 5; t++) {
            const float* m2t = m + 20 + t * 6;
            float acc = 0.f;
            #pragma unroll
            for (int k = 0; k < 3; k++)
                #pragma unroll
                for (int l = 0; l < 3; l++)
                    acc += A[k][l] * m2t[IDX2[k*3+l]];
            o[col + t] = acc;
        }
    }
}

__device__ __forceinline__ void c4_range(const float* m, float* o, int plo, int phi) {
    for (int p = plo; p < phi; p++) {
        int r = PR2[p], s = PS2[p];
        const float* m2r = m + 20 + r * 6;
        const float* m2s = m + 20 + s * 6;
        float B[3][3] = {{0,0,0},{0,0,0},{0,0,0}};
        #pragma unroll
        for (int i = 0; i < 3; i++)
            #pragma unroll
            for (int j = 0; j < 3; j++)
                #pragma unroll
                for (int k = 0; k < 3; k++)
                    B[j][k] += m2r[IDX2[i*3+j]] * m2s[IDX2[i*3+k]];
        int col = CB4[p];
        for (int t = 0; t <= s; t++) {
            const float* m2t = m + 20 + t * 6;
            float acc = 0.f;
            #pragma unroll
            for (int j = 0; j < 3; j++)
                #pragma unroll
                for (int k = 0; k < 3; k++)
                    acc += B[j][k] * m2t[IDX2[j*3+k]];
            o[col + t] = acc;
        }
    }
}

__device__ __forceinline__ void c5_range(const float* m, float* o, int plo, int phi) {
    for (int p = plo; p < phi; p++) {
        int r = PR2[p], s = PS2[p];
        const float* m1r = m + 5 + r * 3;
        const float* m1s = m + 5 + s * 3;
        float P[3][3];
        #pragma unroll
        for (int i = 0; i < 3; i++)
            #pragma unroll
            for (int j = 0; j < 3; j++)
                P[i][j] = m1r[i] * m1s[j];
        int col = 85 + p * 5;
        for (int t = 0; t < 5; t++) {
            const float* m2t = m + 20 + t * 6;
            float acc = 0.f;
            #pragma unroll
            for (int i = 0; i < 3; i++)
                #pragma unroll
                for (int j = 0; j < 3; j++)
                    acc += P[i][j] * m2t[IDX2[i*3+j]];
            o[col + t] = acc;
        }
    }
}

__device__ __forceinline__ void c7_all(const float* m, float* o) {
    for (int r = 0; r < 5; r++) {
        const float* m3r = m + 50 + r * 10;
        for (int s = 0; s < 5; s++) {
            const float* m2s = m + 20 + s * 6;
            float v[3] = {0,0,0};
            #pragma unroll
            for (int i = 0; i < 3; i++)
                #pragma unroll
                for (int j = 0; j < 3; j++)
                    #pragma unroll
                    for (int k = 0; k < 3; k++)
                        v[k] += m3r[IDX3[(i*3+j)*3+k]] * m2s[IDX2[i*3+j]];
            int col = 235 + (r * 5 + s) * 5;
            for (int t = 0; t < 5; t++) {
                const float* m1t = m + 5 + t * 3;
                o[col + t] = v[0]*m1t[0] + v[1]*m1t[1] + v[2]*m1t[2];
            }
        }
    }
}

__device__ __forceinline__ void c0123(const float* m, float* o) {
    for (int r = 0; r < 5; r++) o[r] = m[r];
    const float W2[6]  = {1,2,2,1,2,1};
    const float W3[10] = {1,3,3,3,6,3,1,3,3,1};
    int c1 = 5, c2 = 20, c3 = 35;
    for (int r = 0; r < 5; r++) {
        const float* a1r = m + 5 + r * 3;
        const float* a2r = m + 20 + r * 6;
        const float* a3r = m + 50 + r * 10;
        for (int s = 0; s <= r; s++) {
            const float* a1s = m + 5 + s * 3;
            const float* a2s = m + 20 + s * 6;
            const float* a3s = m + 50 + s * 10;
            float d1 = 0.f, d2 = 0.f, d3 = 0.f;
            #pragma unroll
            for (int u = 0; u < 3; u++)  d1 += a1r[u] * a1s[u];
            #pragma unroll
            for (int u = 0; u < 6; u++)  d2 += W2[u] * a2r[u] * a2s[u];
            #pragma unroll
            for (int u = 0; u < 10; u++) d3 += W3[u] * a3r[u] * a3s[u];
            o[c1++] = d1; o[c2++] = d2; o[c3++] = d3;
        }
    }
}

__device__ __forceinline__ void contract_4wave(
    float sm[64][101], int lane, int w, int a0, int n_atoms, float* __restrict__ out)
{
    int aa = a0 + lane;
    if (aa < n_atoms) {
        const float* m = sm[lane];
        float* o = out + (size_t)aa * 360;
        if (w == 0) {
            c6_range(m, o, 0, 10);
        } else if (w == 1) {
            c6_range(m, o, 10, 15);
            c4_range(m, o, 0, 7);
        } else if (w == 2) {
            c4_range(m, o, 7, 15);
            c5_range(m, o, 0, 15);
        } else {
            c7_all(m, o);
            c0123(m, o);
        }
    }
}

__device__ __forceinline__ void moments_to_out(
    float acc[100], float sm[64][101], int tid, int a0, int n_atoms,
    float* __restrict__ out)
{
    #pragma unroll
    for (int u = 0; u < 100; u++) {
        acc[u] += __shfl_xor(acc[u], 1);
        acc[u] += __shfl_xor(acc[u], 2);
    }
    int g  = tid >> 2;
    int l4 = tid & 3;
    if (a0 + g < n_atoms && l4 == 0) {
        #pragma unroll
        for (int u = 0; u < 100; u++) sm[g][u] = acc[u];
    }
    __syncthreads();
    contract_4wave(sm, tid & 63, tid >> 6, a0, n_atoms, out);
}

// accumulate the 100-moment update for one edge
__device__ __forceinline__ void accum_edge(float acc[100], const float rv[5], const float dn1[3])
{
    float p2[6] = {dn1[0]*dn1[0], dn1[0]*dn1[1], dn1[0]*dn1[2],
                   dn1[1]*dn1[1], dn1[1]*dn1[2], dn1[2]*dn1[2]};
    float p3[10] = {p2[0]*dn1[0], p2[0]*dn1[1], p2[0]*dn1[2],
                    p2[1]*dn1[1], p2[1]*dn1[2], p2[2]*dn1[2],
                    p2[3]*dn1[1], p2[3]*dn1[2], p2[4]*dn1[2],
                    p2[5]*dn1[2]};
    #pragma unroll
    for (int r = 0; r < 5; r++) {
        float rvv = rv[r];
        acc[r] += rvv;
        #pragma unroll
        for (int u = 0; u < 3; u++)  acc[5  + r*3  + u] += rvv * dn1[u];
        #pragma unroll
        for (int u = 0; u < 6; u++)  acc[20 + r*6  + u] += rvv * p2[u];
        #pragma unroll
        for (int u = 0; u < 10; u++) acc[50 + r*10 + u] += rvv * p3[u];
    }
}

// ---------- phase 3: STATIC accumulate+contract (no VGPR cap this time) ----------
__global__ __launch_bounds__(256) void accum_slot_kernel(
    const float4* __restrict__ pay, const float4* __restrict__ radB,
    float* __restrict__ out, int n_atoms)
{
    __shared__ float sm[64][101];
    int tid = threadIdx.x;
    int a0  = blockIdx.x * 64;
    int g   = tid >> 2;
    int l4  = tid & 3;
    int a   = a0 + g;

    float acc[100];
    #pragma unroll
    for (int u = 0; u < 100; u++) acc[u] = 0.f;

    if (a < n_atoms) {
        const float4* prow = pay  + (size_t)a * CAP;
        const float4* rrow = radB + (size_t)a * CAP;
        #pragma unroll 2
        for (int it = 0; it < CAP/4; it++) {
            int es = l4 + it * 4;
            float4 q1 = prow[es];   // {dn0, dn1, dn2, rv4}  (zeros if empty)
            float4 q2 = rrow[es];   // {rv0, rv1, rv2, rv3}
            float dn1[3] = {q1.x, q1.y, q1.z};
            float rv[5]  = {q2.x, q2.y, q2.z, q2.w, q1.w};
            accum_edge(acc, rv, dn1);
        }
    }
    moments_to_out(acc, sm, tid, a0, n_atoms, out);
}

// ---------- fallback accumulate (gather + recompute, r3/r7 style) ----------
__global__ __launch_bounds__(256) void accum_gather_kernel(
    const float4* __restrict__ RZ, const float4* __restrict__ Wp4,
    const int* __restrict__ cnt, const int* __restrict__ bins,
    float* __restrict__ out, int n_atoms)
{
    __shared__ float sm[64][101];
    int tid = threadIdx.x;
    int a0  = blockIdx.x * 64;
    int g   = tid >> 2;
    int l4  = tid & 3;
    int a   = a0 + g;

    float acc[100];
    #pragma unroll
    for (int u = 0; u < 100; u++) acc[u] = 0.f;

    if (a < n_atoms) {
        int cn = cnt[a]; if (cn > CAP) cn = CAP;
        float4 rza = RZ[a];
        int za = __float_as_int(rza.w);
        for (int e = l4; e < cn; e += 4) {
            int i = bins[(size_t)a * CAP + e];
            float4 rzi = RZ[i];
            float dx = rza.x - rzi.x, dy = rza.y - rzi.y, dz = rza.z - rzi.z;
            float dr2 = dx*dx + dy*dy + dz*dz;
            if (!(dr2 < 36.0f)) continue;
            int zi = __float_as_int(rzi.w);
            float rv[5], dn1[3];
            edge_math_raw(dx, dy, dz, zi, za, Wp4, rv, dn1);
            accum_edge(acc, rv, dn1);
        }
    }
    moments_to_out(acc, sm, tid, a0, n_atoms, out);
}

extern "C" void kernel_launch(void* const* d_in, const int* in_sizes, int n_in,
                              void* d_out, int out_size, void* d_ws, size_t ws_size,
                              hipStream_t stream)
{
    const float* R   = (const float*)d_in[0];
    const int*   Z   = (const int*)d_in[1];
    const int*   nbr = (const int*)d_in[2];
    const float* W   = (const float*)d_in[4];
    float* out = (float*)d_out;

    int n_atoms = in_sizes[0] / 3;
    int n_edges = in_sizes[2] / 2;
    int n_wel   = NSP * NSP * 36;

    char* ws = (char*)d_ws;

    size_t szCntPad = (size_t)n_atoms * CPAD * 4;       // 3.2 MB
    size_t szRZ     = (size_t)n_atoms * 16;             // 0.8 MB
    size_t szWp     = (size_t)n_wel * 4;                // 2.0 MB
    size_t szPay16  = (size_t)n_atoms * CAP * 16;       // 38.4 MB
    size_t szRadB   = (size_t)n_atoms * CAP * 16;       // 38.4 MB
    size_t szIdx    = (size_t)n_atoms * CAP * 4;        // 9.6 MB

    size_t needMain = szCntPad + szPay16 + szRadB + szRZ + szWp;   // ~82.8 MB

    if (ws_size >= needMain) {
        int*    cnt  = (int*)ws;
        float4* pay  = (float4*)(ws + szCntPad);
        float4* radB = (float4*)(ws + szCntPad + szPay16);
        float4* RZ   = (float4*)(ws + szCntPad + szPay16 + szRadB);
        float4* Wp4  = (float4*)(ws + szCntPad + szPay16 + szRadB + szRZ);

        hipMemsetAsync(cnt, 0, szCntPad, stream);
        rz_pack_kernel<<<(n_atoms + 255)/256, 256, 0, stream>>>(R, Z, RZ, n_atoms);
        pad_w_kernel<<<(n_wel + 255)/256, 256, 0, stream>>>(W, (float*)Wp4, n_wel);
        edge_light_kernel<<<(n_edges + 255)/256, 256, 0, stream>>>(
            nbr, RZ, cnt, pay, n_edges);
        expand_kernel<<<(n_atoms + 3)/4, 192, 0, stream>>>(
            Z, cnt, pay, Wp4, radB, n_atoms);
        accum_slot_kernel<<<(n_atoms + 63)/64, 256, 0, stream>>>(
            pay, radB, out, n_atoms);
    } else {
        // fallback: round-3 footprint (~14.6 MB with CAP=48)
        int*    cnt  = (int*)ws;
        int*    bins = (int*)(ws + 204800);
        float4* RZ   = (float4*)(ws + 204800 + szIdx);
        float4* Wp4  = (float4*)(ws + 204800 + szIdx + szRZ);

        hipMemsetAsync(cnt, 0, (size_t)n_atoms * 4, stream);
        rz_pack_kernel<<<(n_atoms + 255)/256, 256, 0, stream>>>(R, Z, RZ, n_atoms);
        pad_w_kernel<<<(n_wel + 255)/256, 256, 0, stream>>>(W, (float*)Wp4, n_wel);
        scatter_bins_kernel<<<(n_edges + 255)/256, 256, 0, stream>>>(nbr, cnt, bins, n_edges);
        accum_gather_kernel<<<(n_atoms + 63)/64, 256, 0, stream>>>(
            RZ, Wp4, cnt, bins, out, n_atoms);
    }
}

// Round 12
// 128.602 us; speedup vs baseline: 1.9820x; 1.0666x over previous
//
#include <hip/hip_runtime.h>
#include <cstdint>
#include <cstddef>

#define CAP 48
#define NSP 119
#define CPAD 16   // padded cnt stride (ints) = 64B/counter; only word 0 of each group is used

__device__ constexpr int IDX2[9]  = {0,1,2, 1,3,4, 2,4,5};
__device__ constexpr int IDX3[27] = {0,1,2, 1,3,4, 2,4,5,
                                     1,3,4, 3,6,7, 4,7,8,
                                     2,4,5, 4,7,8, 5,8,9};
__device__ constexpr int PR2[15] = {0,1,1,2,2,2,3,3,3,3,4,4,4,4,4};
__device__ constexpr int PS2[15] = {0,0,1,0,1,2,0,1,2,3,0,1,2,3,4};
__device__ constexpr int CB4[15] = {50,51,52,54,55,57,60,61,63,66,70,71,73,76,80};

// ---------- fused prep: zero cnt words + pack RZ + pad W (one launch) ----------
__global__ __launch_bounds__(256) void prep_kernel(
    const float* __restrict__ R, const int* __restrict__ Z,
    const float* __restrict__ W,
    int* __restrict__ cnt, float4* __restrict__ RZ, float* __restrict__ Wp,
    int n_atoms, int n_wel)
{
    int t = blockIdx.x * blockDim.x + threadIdx.x;
    if (t < n_atoms) {
        cnt[t * CPAD] = 0;
        RZ[t] = make_float4(R[3*t], R[3*t+1], R[3*t+2], __int_as_float(Z[t]));
    }
    if (t < n_wel) {
        int rc = t / 36;
        int u  = t - rc * 36;
        Wp[t] = (u < 35) ? W[rc * 35 + u] : 0.f;
    }
}

// ---------- phase 1: LIGHT edge scatter — 16B {dx,dy,dz,Zi} into slot's 1st quad ----------
__global__ __launch_bounds__(256) void edge_light_kernel(
    const int* __restrict__ nbr, const float4* __restrict__ RZ,
    int* __restrict__ cnt, float4* __restrict__ pay2, int n_edges)
{
    int e = blockIdx.x * blockDim.x + threadIdx.x;
    if (e >= n_edges) return;
    int i = nbr[e];
    int j = nbr[n_edges + e];
    if (i == j) return;
    float4 rzi = RZ[i];
    float4 rzj = RZ[j];
    float dx = rzj.x - rzi.x, dy = rzj.y - rzi.y, dz = rzj.z - rzi.z;
    float dr2 = dx*dx + dy*dy + dz*dz;
    if (!(dr2 < 36.0f)) return;          // cutoff == 0 outside R_MAX

    int pos = atomicAdd(&cnt[j * CPAD], 1);
    if (pos < CAP) {
        pay2[((size_t)j * CAP + pos) * 2] = make_float4(dx, dy, dz, rzi.w); // rzi.w = Zi bits
    }
}

// ---------- phase 2: slot-parallel finalize IN PLACE -> {dn,rv4}{rv0..3} ----------
__global__ __launch_bounds__(192) void expand_kernel(
    const int* __restrict__ Z,
    const int* __restrict__ cnt, float4* __restrict__ pay2,
    const float4* __restrict__ Wp4, int n_atoms)
{
    int tid = threadIdx.x;
    int a    = blockIdx.x * 4 + tid / CAP;
    int slot = tid % CAP;
    if (a >= n_atoms) return;
    int cn = cnt[a * CPAD]; if (cn > CAP) cn = CAP;
    if (slot >= cn) return;

    size_t idx = (size_t)a * CAP + slot;
    float4 q = pay2[2 * idx];
    float dr = sqrtf(q.x*q.x + q.y*q.y + q.z*q.z);
    float inv = 1.0f / (dr + 1e-5f);

    const float betta      = 49.0f/36.0f;
    const float rad_norm   = 0.96481270f;
    const float embed_norm = 0.37796447f;
    const float PI_F       = 3.14159265358979f;
    float cut = 0.5f * (__cosf(PI_F * dr * (1.0f/6.0f)) + 1.0f) * rad_norm * embed_norm;

    float basis[7];
    #pragma unroll
    for (int n = 0; n < 7; n++) {
        float d = dr - (0.5f + (5.5f/7.0f) * (float)n);
        basis[n] = __expf(-betta * d * d);
    }

    int zi = __float_as_int(q.w);
    int za = Z[a];
    int base4 = (zi * NSP + za) * 9;

    float rad[5] = {0,0,0,0,0};
    #pragma unroll
    for (int qq = 0; qq < 9; qq++) {
        float4 wq = Wp4[base4 + qq];
        #pragma unroll
        for (int c = 0; c < 4; c++) {
            int f = 4*qq + c;
            if (f < 35) {
                float wv = (c==0) ? wq.x : (c==1) ? wq.y : (c==2) ? wq.z : wq.w;
                rad[f/7] += basis[f%7] * wv;
            }
        }
    }
    pay2[2*idx    ] = make_float4(q.x*inv, q.y*inv, q.z*inv, rad[4]*cut);
    pay2[2*idx + 1] = make_float4(rad[0]*cut, rad[1]*cut, rad[2]*cut, rad[3]*cut);
}

// ---------- fallback (round-3 style): scatter idx only ----------
__global__ __launch_bounds__(256) void scatter_bins_kernel(
    const int* __restrict__ nbr, int* __restrict__ cnt,
    int* __restrict__ bins, int n_edges)
{
    int e = blockIdx.x * blockDim.x + threadIdx.x;
    if (e >= n_edges) return;
    int i = nbr[e];
    int j = nbr[n_edges + e];
    if (i == j) return;
    int pos = atomicAdd(&cnt[j], 1);
    if (pos < CAP) bins[(size_t)j * CAP + pos] = i;
}

__device__ __forceinline__ void edge_math_raw(
    float dx, float dy, float dz, int zi, int za,
    const float4* __restrict__ Wp4, float rv[5], float dn[3])
{
    float dr = sqrtf(dx*dx + dy*dy + dz*dz);
    float inv = 1.0f / (dr + 1e-5f);
    dn[0] = dx*inv; dn[1] = dy*inv; dn[2] = dz*inv;

    const float betta      = 49.0f/36.0f;
    const float rad_norm   = 0.96481270f;
    const float embed_norm = 0.37796447f;
    const float PI_F       = 3.14159265358979f;
    float cut = 0.5f * (__cosf(PI_F * dr * (1.0f/6.0f)) + 1.0f) * rad_norm * embed_norm;

    float basis[7];
    #pragma unroll
    for (int n = 0; n < 7; n++) {
        float d = dr - (0.5f + (5.5f/7.0f) * (float)n);
        basis[n] = __expf(-betta * d * d);
    }

    int base4 = (zi * NSP + za) * 9;
    float rad[5] = {0,0,0,0,0};
    #pragma unroll
    for (int q = 0; q < 9; q++) {
        float4 wq = Wp4[base4 + q];
        #pragma unroll
        for (int c = 0; c < 4; c++) {
            int f = 4*q + c;
            if (f < 35) {
                float wv = (c==0) ? wq.x : (c==1) ? wq.y : (c==2) ? wq.z : wq.w;
                rad[f/7] += basis[f%7] * wv;
            }
        }
    }
    #pragma unroll
    for (int r = 0; r < 5; r++) rv[r] = rad[r] * cut;
}

// ---------- contraction helpers (operands in LDS) ----------
__device__ __forceinline__ void c6_range(const float* m, float* o, int plo, int phi) {
    for (int p = plo; p < phi; p++) {
        int r = PR2[p], s = PS2[p];
        const float* m3r = m + 50 + r * 10;
        const float* m3s = m + 50 + s * 10;
        float A[3][3] = {{0,0,0},{0,0,0},{0,0,0}};
        #pragma unroll
        for (int i = 0; i < 3; i++)
            #pragma unroll
            for (int j = 0; j < 3; j++)
                #pragma unroll
                for (int k = 0; k < 3; k++)
                    #pragma unroll
                    for (int l = 0; l < 3; l++)
                        A[k][l] += m3r[IDX3[(i*3+j)*3+k]] * m3s[IDX3[(i*3+j)*3+l]];
        int col = 160 + p * 5;
        for (int t = 0; t < 5; t++) {
            const float* m2t = m + 20 + t * 6;
            float acc = 0.f;
            #pragma unroll
            for (int k = 0; k < 3; k++)
                #pragma unroll
                for (int l = 0; l < 3; l++)
                    acc += A[k][l] * m2t[IDX2[k*3+l]];
            o[col + t] = acc;
        }
    }
}

__device__ __forceinline__ void c4_range(const float* m, float* o, int plo, int phi) {
    for (int p = plo; p < phi; p++) {
        int r = PR2[p], s = PS2[p];
        const float* m2r = m + 20 + r * 6;
        const float* m2s = m + 20 + s * 6;
        float B[3][3] = {{0,0,0},{0,0,0},{0,0,0}};
        #pragma unroll
        for (int i = 0; i < 3; i++)
            #pragma unroll
            for (int j = 0; j < 3; j++)
                #pragma unroll
                for (int k = 0; k < 3; k++)
                    B[j][k] += m2r[IDX2[i*3+j]] * m2s[IDX2[i*3+k]];
        int col = CB4[p];
        for (int t = 0; t <= s; t++) {
            const float* m2t = m + 20 + t * 6;
            float acc = 0.f;
            #pragma unroll
            for (int j = 0; j < 3; j++)
                #pragma unroll
                for (int k = 0; k < 3; k++)
                    acc += B[j][k] * m2t[IDX2[j*3+k]];
            o[col + t] = acc;
        }
    }
}

__device__ __forceinline__ void c5_range(const float* m, float* o, int plo, int phi) {
    for (int p = plo; p < phi; p++) {
        int r = PR2[p], s = PS2[p];
        const float* m1r = m + 5 + r * 3;
        const float* m1s = m + 5 + s * 3;
        float P[3][3];
        #pragma unroll
        for (int i = 0; i < 3; i++)
            #pragma unroll
            for (int j = 0; j < 3; j++)
                P[i][j] = m1r[i] * m1s[j];
        int col = 85 + p * 5;
        for (int t = 0; t < 5; t++) {
            const float* m2t = m + 20 + t * 6;
            float acc = 0.f;
            #pragma unroll
            for (int i = 0; i < 3; i++)
                #pragma unroll
                for (int j = 0; j < 3; j++)
                    acc += P[i][j] * m2t[IDX2[i*3+j]];
            o[col + t] = acc;
        }
    }
}

__device__ __forceinline__ void c7_all(const float* m, float* o) {
    for (int r = 0; r < 5; r++) {
        const float* m3r = m + 50 + r * 10;
        for (int s = 0; s < 5; s++) {
            const float* m2s = m + 20 + s * 6;
            float v[3] = {0,0,0};
            #pragma unroll
            for (int i = 0; i < 3; i++)
                #pragma unroll
                for (int j = 0; j < 3; j++)
                    #pragma unroll
                    for (int k = 0; k < 3; k++)
                        v[k] += m3r[IDX3[(i*3+j)*3+k]] * m2s[IDX2[i*3+j]];
            int col = 235 + (r * 5 + s) * 5;
            for (int t = 0; t < 5; t++) {
                const float* m1t = m + 5 + t * 3;
                o[col + t] = v[0]*m1t[0] + v[1]*m1t[1] + v[2]*m1t[2];
            }
        }
    }
}

__device__ __forceinline__ void c0123(const float* m, float* o) {
    for (int r = 0; r < 5; r++) o[r] = m[r];
    const float W2[6]  = {1,2,2,1,2,1};
    const float W3[10] = {1,3,3,3,6,3,1,3,3,1};
    int c1 = 5, c2 = 20, c3 = 35;
    for (int r = 0; r < 5; r++) {
        const float* a1r = m + 5 + r * 3;
        const float* a2r = m + 20 + r * 6;
        const float* a3r = m + 50 + r * 10;
        for (int s = 0; s <= r; s++) {
            const float* a1s = m + 5 + s * 3;
            const float* a2s = m + 20 + s * 6;
            const float* a3s = m + 50 + s * 10;
            float d1 = 0.f, d2 = 0.f, d3 = 0.f;
            #pragma unroll
            for (int u = 0; u < 3; u++)  d1 += a1r[u] * a1s[u];
            #pragma unroll
            for (int u = 0; u < 6; u++)  d2 += W2[u] * a2r[u] * a2s[u];
            #pragma unroll
            for (int u = 0; u < 10; u++) d3 += W3[u] * a3r[u] * a3s[u];
            o[c1++] = d1; o[c2++] = d2; o[c3++] = d3;
        }
    }
}

__device__ __forceinline__ void contract_4wave(
    float sm[64][101], int lane, int w, int a0, int n_atoms, float* __restrict__ out)
{
    int aa = a0 + lane;
    if (aa < n_atoms) {
        const float* m = sm[lane];
        float* o = out + (size_t)aa * 360;
        if (w == 0) {
            c6_range(m, o, 0, 10);
        } else if (w == 1) {
            c6_range(m, o, 10, 15);
            c4_range(m, o, 0, 7);
        } else if (w == 2) {
            c4_range(m, o, 7, 15);
            c5_range(m, o, 0, 15);
        } else {
            c7_all(m, o);
            c0123(m, o);
        }
    }
}

__device__ __forceinline__ void moments_to_out(
    float acc[100], float sm[64][101], int tid, int a0, int n_atoms,
    float* __restrict__ out)
{
    #pragma unroll
    for (int u = 0; u < 100; u++) {
        acc[u] += __shfl_xor(acc[u], 1);
        acc[u] += __shfl_xor(acc[u], 2);
    }
    int g  = tid >> 2;
    int l4 = tid & 3;
    if (a0 + g < n_atoms && l4 == 0) {
        #pragma unroll
        for (int u = 0; u < 100; u++) sm[g][u] = acc[u];
    }
    __syncthreads();
    contract_4wave(sm, tid & 63, tid >> 6, a0, n_atoms, out);
}

// accumulate the 100-moment update for one edge
__device__ __forceinline__ void accum_edge(float acc[100], const float rv[5], const float dn1[3])
{
    float p2[6] = {dn1[0]*dn1[0], dn1[0]*dn1[1], dn1[0]*dn1[2],
                   dn1[1]*dn1[1], dn1[1]*dn1[2], dn1[2]*dn1[2]};
    float p3[10] = {p2[0]*dn1[0], p2[0]*dn1[1], p2[0]*dn1[2],
                    p2[1]*dn1[1], p2[1]*dn1[2], p2[2]*dn1[2],
                    p2[3]*dn1[1], p2[3]*dn1[2], p2[4]*dn1[2],
                    p2[5]*dn1[2]};
    #pragma unroll
    for (int r = 0; r < 5; r++) {
        float rvv = rv[r];
        acc[r] += rvv;
        #pragma unroll
        for (int u = 0; u < 3; u++)  acc[5  + r*3  + u] += rvv * dn1[u];
        #pragma unroll
        for (int u = 0; u < 6; u++)  acc[20 + r*6  + u] += rvv * p2[u];
        #pragma unroll
        for (int u = 0; u < 10; u++) acc[50 + r*10 + u] += rvv * p3[u];
    }
}

// ---------- phase 3: accumulate+contract — single interleaved stream (r6 pattern) ----------
__global__ __launch_bounds__(256) void accum_slot_kernel(
    const int* __restrict__ cnt, const float4* __restrict__ pay2,
    float* __restrict__ out, int n_atoms)
{
    __shared__ float sm[64][101];
    int tid = threadIdx.x;
    int a0  = blockIdx.x * 64;
    int g   = tid >> 2;
    int l4  = tid & 3;
    int a   = a0 + g;

    float acc[100];
    #pragma unroll
    for (int u = 0; u < 100; u++) acc[u] = 0.f;

    if (a < n_atoms) {
        int cn = cnt[a * CPAD]; if (cn > CAP) cn = CAP;
        const float4* row = pay2 + (size_t)a * CAP * 2;
        // 4-lane group reads 4 consecutive 32B slots -> 128B contiguous per iteration
        for (int es = l4; es < cn; es += 4) {
            float4 q1 = row[2*es    ];   // {dn0, dn1, dn2, rv4}
            float4 q2 = row[2*es + 1];   // {rv0, rv1, rv2, rv3}
            float dn1[3] = {q1.x, q1.y, q1.z};
            float rv[5]  = {q2.x, q2.y, q2.z, q2.w, q1.w};
            accum_edge(acc, rv, dn1);
        }
    }
    moments_to_out(acc, sm, tid, a0, n_atoms, out);
}

// ---------- fallback accumulate (gather + recompute, r3 style) ----------
__global__ __launch_bounds__(256) void accum_gather_kernel(
    const float4* __restrict__ RZ, const float4* __restrict__ Wp4,
    const int* __restrict__ cnt, const int* __restrict__ bins,
    float* __restrict__ out, int n_atoms)
{
    __shared__ float sm[64][101];
    int tid = threadIdx.x;
    int a0  = blockIdx.x * 64;
    int g   = tid >> 2;
    int l4  = tid & 3;
    int a   = a0 + g;

    float acc[100];
    #pragma unroll
    for (int u = 0; u < 100; u++) acc[u] = 0.f;

    if (a < n_atoms) {
        int cn = cnt[a]; if (cn > CAP) cn = CAP;
        float4 rza = RZ[a];
        int za = __float_as_int(rza.w);
        for (int e = l4; e < cn; e += 4) {
            int i = bins[(size_t)a * CAP + e];
            float4 rzi = RZ[i];
            float dx = rza.x - rzi.x, dy = rza.y - rzi.y, dz = rza.z - rzi.z;
            float dr2 = dx*dx + dy*dy + dz*dz;
            if (!(dr2 < 36.0f)) continue;
            int zi = __float_as_int(rzi.w);
            float rv[5], dn1[3];
            edge_math_raw(dx, dy, dz, zi, za, Wp4, rv, dn1);
            accum_edge(acc, rv, dn1);
        }
    }
    moments_to_out(acc, sm, tid, a0, n_atoms, out);
}

extern "C" void kernel_launch(void* const* d_in, const int* in_sizes, int n_in,
                              void* d_out, int out_size, void* d_ws, size_t ws_size,
                              hipStream_t stream)
{
    const float* R   = (const float*)d_in[0];
    const int*   Z   = (const int*)d_in[1];
    const int*   nbr = (const int*)d_in[2];
    const float* W   = (const float*)d_in[4];
    float* out = (float*)d_out;

    int n_atoms = in_sizes[0] / 3;
    int n_edges = in_sizes[2] / 2;
    int n_wel   = NSP * NSP * 36;

    char* ws = (char*)d_ws;

    size_t szCntPad = (size_t)n_atoms * CPAD * 4;       // 3.2 MB
    size_t szRZ     = (size_t)n_atoms * 16;             // 0.8 MB
    size_t szWp     = (size_t)n_wel * 4;                // 2.0 MB
    size_t szPay2   = (size_t)n_atoms * CAP * 32;       // 76.8 MB (32B per slot, interleaved)
    size_t szIdx    = (size_t)n_atoms * CAP * 4;        // 9.6 MB

    size_t needMain = szCntPad + szPay2 + szRZ + szWp;  // ~82.8 MB (== r9's proven footprint)

    if (ws_size >= needMain) {
        int*    cnt  = (int*)ws;
        float4* pay2 = (float4*)(ws + szCntPad);
        float4* RZ   = (float4*)(ws + szCntPad + szPay2);
        float4* Wp4  = (float4*)(ws + szCntPad + szPay2 + szRZ);

        int prep_n = (n_wel > n_atoms) ? n_wel : n_atoms;
        prep_kernel<<<(prep_n + 255)/256, 256, 0, stream>>>(
            R, Z, W, cnt, RZ, (float*)Wp4, n_atoms, n_wel);
        edge_light_kernel<<<(n_edges + 255)/256, 256, 0, stream>>>(
            nbr, RZ, cnt, pay2, n_edges);
        expand_kernel<<<(n_atoms + 3)/4, 192, 0, stream>>>(
            Z, cnt, pay2, Wp4, n_atoms);
        accum_slot_kernel<<<(n_atoms + 63)/64, 256, 0, stream>>>(
            cnt, pay2, out, n_atoms);
    } else {
        // fallback: round-3 footprint (~14.6 MB with CAP=48)
        int*    cnt  = (int*)ws;
        int*    bins = (int*)(ws + 204800);
        float4* RZ   = (float4*)(ws + 204800 + szIdx);
        float4* Wp4  = (float4*)(ws + 204800 + szIdx + szRZ);

        hipMemsetAsync(cnt, 0, (size_t)n_atoms * 4, stream);
        prep_kernel<<<(n_wel + 255)/256, 256, 0, stream>>>(
            R, Z, W, cnt, RZ, (float*)Wp4, 0 /*cnt/RZ handled below*/, n_wel);
        // RZ pack for fallback (prep above only padded W when n_atoms arg is 0)
        // simple dedicated pass:
        {
            struct Local {
                static __global__ void dummy() {}
            };
        }
        // pack RZ via prep-style loop: reuse prep_kernel with n_wel=0
        prep_kernel<<<(n_atoms + 255)/256, 256, 0, stream>>>(
            R, Z, W, cnt, RZ, (float*)Wp4, n_atoms, 0);
        scatter_bins_kernel<<<(n_edges + 255)/256, 256, 0, stream>>>(nbr, cnt, bins, n_edges);
        accum_gather_kernel<<<(n_atoms + 63)/64, 256, 0, stream>>>(
            RZ, Wp4, cnt, bins, out, n_atoms);
    }
}